// Round 10
// baseline (874.759 us; speedup 1.0000x reference)
//
#include <hip/hip_runtime.h>

#define BSZ 32
#define NN 24
#define TT 12
#define FF 3
#define KK 3
#define COUT 12
#define DIN 313          // N*COUT + N + 1
#define HID 3756         // DIN*T
#define H4 15024         // 4*HID
#define KP 3776          // HID padded to 118*32
#define KPI 320          // DIN padded to 10*32
#define NTILES 470       // ceil(15024/32)
#define NB 235           // ceil(3756/16) j-tiles for fused step

using short8 = __attribute__((ext_vector_type(8))) short;
using f32x4  = __attribute__((ext_vector_type(4))) float;

__device__ inline unsigned short f2bf(float f){
  union{float f; unsigned u;} v; v.f=f;
  unsigned u=v.u;
  return (unsigned short)((u + 0x7FFFu + ((u>>16)&1u))>>16);
}
// float -> OCP e4m3fn, RNE, clamp to +-448
__device__ inline unsigned char f2e4m3(float x){
  float ax=fabsf(x);
  unsigned char s = (x<0.f)?0x80:0;
  if(!(ax>0.f)) return s;
  if(ax>=448.f) return s|0x7E;
  int e; frexpf(ax,&e);             // ax in [2^(e-1), 2^e)
  int shift=e-1;
  if(shift<-6){                     // subnormal: quantum 2^-9
    int m=(int)rintf(ldexpf(ax,9)); // 0..8 (8 rolls into min normal)
    return s|(unsigned char)m;
  }
  float q=ldexpf(ax,3-shift);       // in [8,16)
  int mi=(int)rintf(q);             // 8..16 (16 rolls to next exponent)
  int code=((shift+7)<<3)+(mi-8);
  if(code>0x7E) code=0x7E;
  return s|(unsigned char)code;
}
__device__ inline f32x4 mfma16(short8 a, short8 b, f32x4 c){
  return __builtin_amdgcn_mfma_f32_16x16x32_bf16(a,b,c,0,0,0);
}
__device__ inline f32x4 mfma8(long a, long b, f32x4 c){
  return __builtin_amdgcn_mfma_f32_16x16x32_fp8_fp8(a,b,c,0,0,0);
}
__device__ inline float sigm(float x){ return 1.f/(1.f+expf(-x)); }

#define WSCALE 64.f
#define WINV   (1.f/64.f)

// ---------- fused fp32->bf16(+fp8) conversion: W_hh rows + h0 rows ----------
__global__ void k_convall(const float* __restrict__ W, const float* __restrict__ h0f,
    unsigned short* __restrict__ Wb, unsigned short* __restrict__ hb0,
    unsigned short* __restrict__ hb1, unsigned char* __restrict__ Wf8,
    unsigned char* __restrict__ hf80, unsigned char* __restrict__ hf81){
  const int g4 = KP>>2;                 // 944 groups of 4
  long total = (long)(H4+BSZ)*g4;
  for(long i=(long)blockIdx.x*blockDim.x+threadIdx.x; i<total; i+=(long)gridDim.x*blockDim.x){
    int g=(int)(i%g4); int r=(int)(i/g4);
    int k=g*4;
    const float* src;
    bool isW = r<H4;
    src = isW ? (W + (long)r*HID) : (h0f + (long)(r-H4)*HID);
    float vv[4];
    if(k+3<HID){
      float4 v=*(const float4*)(src+k);
      vv[0]=v.x; vv[1]=v.y; vv[2]=v.z; vv[3]=v.w;
    } else {
      #pragma unroll
      for(int q=0;q<4;q++){ int kk=k+q; vv[q]=(kk<HID)? src[kk] : 0.f; }
    }
    ushort4 o;
    o.x=f2bf(vv[0]); o.y=f2bf(vv[1]); o.z=f2bf(vv[2]); o.w=f2bf(vv[3]);
    uchar4 o8;
    if(isW){
      o8.x=f2e4m3(vv[0]*WSCALE); o8.y=f2e4m3(vv[1]*WSCALE);
      o8.z=f2e4m3(vv[2]*WSCALE); o8.w=f2e4m3(vv[3]*WSCALE);
      *(ushort4*)(Wb + (long)r*KP + k) = o;
      *(uchar4*)(Wf8 + (long)r*KP + k) = o8;
    } else {
      o8.x=f2e4m3(vv[0]); o8.y=f2e4m3(vv[1]);
      o8.z=f2e4m3(vv[2]); o8.w=f2e4m3(vv[3]);
      int rr=r-H4;
      *(ushort4*)(hb0 + (long)rr*KP + k) = o;
      *(ushort4*)(hb1 + (long)rr*KP + k) = o;
      *(uchar4*)(hf80 + (long)rr*KP + k) = o8;
      *(uchar4*)(hf81 + (long)rr*KP + k) = o8;
    }
  }
}

// ---------- spatial + temporal attention (pre batch-softmax), per batch ----------
__global__ void k_attn(const float* __restrict__ X, const float* __restrict__ sa_W1,
   const float* __restrict__ sa_W2, const float* __restrict__ sa_W3,
   const float* __restrict__ sa_bs, const float* __restrict__ sa_Vs,
   const float* __restrict__ ta_U1, const float* __restrict__ ta_U2,
   const float* __restrict__ ta_U3, const float* __restrict__ ta_be,
   const float* __restrict__ ta_Ve,
   float* __restrict__ SA_pre, float* __restrict__ TA_pre){
  int b=blockIdx.x, tid=threadIdx.x;
  __shared__ float lin[864];            // raw X[b], layout [n][t][f]
  __shared__ float lhs[NN*TT];
  __shared__ float rhs[TT*NN];
  __shared__ float P[NN*NN];
  __shared__ float S[NN*NN];
  __shared__ float lhsT[TT*NN];
  __shared__ float rhsT[NN*TT];
  __shared__ float PT[TT*TT];
  __shared__ float E[TT*TT];
  for(int i=tid;i<864;i+=256) lin[i]=X[b*864+i];
  __syncthreads();
  for(int i=tid;i<NN*TT;i+=256){ int n=i/TT, t=i%TT;
    float acc=0;
    #pragma unroll
    for(int f=0;f<FF;f++){
      float t1=0;
      for(int u=0;u<TT;u++) t1 += lin[n*36+u*3+f]*sa_W1[u];
      acc += t1*sa_W2[f*TT+t];
    }
    lhs[n*TT+t]=acc;
    float r=0;
    #pragma unroll
    for(int f=0;f<FF;f++) r += sa_W3[f]*lin[n*36+t*3+f];
    rhs[t*NN+n]=r;
  }
  for(int i=tid;i<TT*NN;i+=256){ int t=i/NN, n=i%NN;
    float acc=0;
    #pragma unroll
    for(int f=0;f<FF;f++){
      float t1=0;
      for(int m=0;m<NN;m++) t1 += lin[m*36+t*3+f]*ta_U1[m];
      acc += t1*ta_U2[f*NN+n];
    }
    lhsT[t*NN+n]=acc;
    float r=0;
    #pragma unroll
    for(int f=0;f<FF;f++) r += ta_U3[f]*lin[n*36+t*3+f];
    rhsT[n*TT+t]=r;
  }
  __syncthreads();
  for(int i=tid;i<NN*NN;i+=256){ int n=i/NN,m=i%NN;
    float a=0;
    for(int t=0;t<TT;t++) a+=lhs[n*TT+t]*rhs[t*NN+m];
    P[i]=sigm(a+sa_bs[i]);
  }
  for(int i=tid;i<TT*TT;i+=256){ int t=i/TT,u=i%TT;
    float a=0;
    for(int n=0;n<NN;n++) a+=lhsT[t*NN+n]*rhsT[n*TT+u];
    PT[i]=sigm(a+ta_be[i]);
  }
  __syncthreads();
  for(int i=tid;i<NN*NN;i+=256){ int n=i/NN,k=i%NN;
    float a=0;
    for(int m=0;m<NN;m++) a+=sa_Vs[n*NN+m]*P[m*NN+k];
    S[i]=a;
  }
  for(int i=tid;i<TT*TT;i+=256){ int t=i/TT,v=i%TT;
    float a=0;
    for(int u=0;u<TT;u++) a+=ta_Ve[t*TT+u]*PT[u*TT+v];
    E[i]=a;
  }
  __syncthreads();
  if(tid<NN){ int k=tid;
    float mx=-1e30f;
    for(int n=0;n<NN;n++) mx=fmaxf(mx,S[n*NN+k]);
    float sm=0;
    for(int n=0;n<NN;n++) sm+=__expf(S[n*NN+k]-mx);
    for(int n=0;n<NN;n++){
      float v=__expf(S[n*NN+k]-mx)/sm;
      SA_pre[b*576+n*NN+k]=sigm(v);
    }
  }
  if(tid>=32 && tid<32+TT){ int v=tid-32;
    float mx=-1e30f;
    for(int t=0;t<TT;t++) mx=fmaxf(mx,E[t*TT+v]);
    float sm=0;
    for(int t=0;t<TT;t++) sm+=__expf(E[t*TT+v]-mx);
    for(int t=0;t<TT;t++){
      float e=__expf(E[t*TT+v]-mx)/sm;
      TA_pre[b*144+t*TT+v]=sigm(e);
    }
  }
}

// ---------- softmax over batch axis; s_a also written to OUTPUT as float ----------
__global__ void k_bsoftmax(const float* __restrict__ SA_pre, const float* __restrict__ TA_pre,
    float* __restrict__ s_a, float* __restrict__ t_a, float* __restrict__ out_sa){
  int i=blockIdx.x*blockDim.x+threadIdx.x;
  if(i<576){
    float mx=-1e30f;
    for(int b=0;b<BSZ;b++) mx=fmaxf(mx,SA_pre[b*576+i]);
    float sm=0;
    for(int b=0;b<BSZ;b++) sm+=__expf(SA_pre[b*576+i]-mx);
    for(int b=0;b<BSZ;b++){
      float v=__expf(SA_pre[b*576+i]-mx)/sm;
      s_a[b*576+i]=v;
      out_sa[b*576+i]=v;
    }
  } else if(i<720){
    int j=i-576;
    float mx=-1e30f;
    for(int b=0;b<BSZ;b++) mx=fmaxf(mx,TA_pre[b*144+j]);
    float sm=0;
    for(int b=0;b<BSZ;b++) sm+=__expf(TA_pre[b*144+j]-mx);
    for(int b=0;b<BSZ;b++) t_a[b*144+j]=__expf(TA_pre[b*144+j]-mx)/sm;
  }
}

// ---------- graph conv + LN + temporal mix + input layer, per batch ----------
__global__ void k_graph(const float* __restrict__ X, const float* __restrict__ cheb,
  const float* __restrict__ s_a, const float* __restrict__ t_a,
  const float* __restrict__ theta, const float* __restrict__ cheb_bias,
  const float* __restrict__ ln_g, const float* __restrict__ ln_b,
  const float* __restrict__ liw, const float* __restrict__ lib,
  float* __restrict__ x_in){
  int b=blockIdx.x, tid=threadIdx.x;
  __shared__ float lin[864];
  __shared__ float A2[KK*NN*NN];
  __shared__ float rg[KK*NN*FF*TT];
  __shared__ float xc[NN*COUT*TT];
  __shared__ float xres[DIN*TT];
  __shared__ float ta_s[TT*TT];
  for(int i=tid;i<864;i+=320) lin[i]=X[b*864+i];
  for(int i=tid;i<KK*NN*NN;i+=320){ int mn=i%576; A2[i]=cheb[i]*s_a[b*576+mn]; }
  for(int i=tid;i<144;i+=320) ta_s[i]=t_a[b*144+i];
  __syncthreads();
  for(int i=tid;i<KK*NN*FF*TT;i+=320){
    int t=i%TT, f=(i/TT)%FF, n=(i/36)%NN, k=i/864;
    float a=0;
    for(int m=0;m<NN;m++) a+=A2[k*576+m*NN+n]*lin[m*36+f*TT+t];
    rg[i]=a;
  }
  __syncthreads();
  for(int i=tid;i<NN*COUT*TT;i+=320){
    int t=i%TT, o=(i/TT)%COUT, n=i/(COUT*TT);
    float a=cheb_bias[o];
    #pragma unroll
    for(int k=0;k<KK;k++)
      #pragma unroll
      for(int f=0;f<FF;f++)
        a += rg[((k*NN+n)*FF+f)*TT+t]*theta[(k*FF+f)*COUT+o];
    xc[i]=fmaxf(a,0.f);
  }
  __syncthreads();
  if(tid<NN*COUT){
    float mu=0;
    for(int t=0;t<TT;t++) mu+=xc[tid*TT+t];
    mu*=(1.f/12.f);
    float var=0;
    for(int t=0;t<TT;t++){ float d=xc[tid*TT+t]-mu; var+=d*d; }
    var*=(1.f/12.f);
    float inv=rsqrtf(var+1e-5f);
    for(int t=0;t<TT;t++) xc[tid*TT+t]=(xc[tid*TT+t]-mu)*inv*ln_g[t]+ln_b[t];
  }
  __syncthreads();
  for(int i=tid;i<NN*COUT;i+=320){
    for(int v=0;v<TT;v++){
      float a=0;
      for(int t=0;t<TT;t++) a+=xc[i*TT+t]*ta_s[t*TT+v];
      xres[i*TT+v]=a;
    }
  }
  for(int i=tid;i<25*TT;i+=320){
    int r=i/TT, t=i%TT;
    float v=(r<NN)? lin[r*36+t*3+0] : lin[t*3+1];
    xres[(288+r)*TT+t]=v;
  }
  __syncthreads();
  for(int i=tid;i<DIN;i+=320){
    for(int t=0;t<TT;t++){
      float a=lib[t];
      #pragma unroll
      for(int u=0;u<TT;u++) a+=xres[i*TT+u]*liw[t*TT+u];
      x_in[((long)b*DIN+i)*TT+t]=a;
    }
  }
}

// ---------- per-(t,b): alpha softmax gate, xi -> bf16 padded [t*32+b][KPI] ----------
__global__ void __launch_bounds__(512) k_alpha(const float* __restrict__ x_in,
    const float* __restrict__ sa2_w, const float* __restrict__ sa2_b,
    unsigned short* __restrict__ xi_b){
  int blk=blockIdx.x; int t=blk>>5, b=blk&31; int tid=threadIdx.x;
  __shared__ float xt[DIN];
  __shared__ float red[512];
  if(tid<DIN) xt[tid]=x_in[((long)b*DIN+tid)*TT+t];
  __syncthreads();
  float z=-1e30f, e=0.f;
  if(tid<DIN){
    float a=sa2_b[tid];
    const float* wr=sa2_w+(long)tid*DIN;
    for(int i=0;i<DIN;i++) a+=xt[i]*wr[i];
    z=sigm(a);
  }
  red[tid]=z; __syncthreads();
  for(int off=256;off>0;off>>=1){ if(tid<off) red[tid]=fmaxf(red[tid],red[tid+off]); __syncthreads(); }
  float mx=red[0]; __syncthreads();
  e=(tid<DIN)?__expf(z-mx):0.f;
  red[tid]=e; __syncthreads();
  for(int off=256;off>0;off>>=1){ if(tid<off) red[tid]+=red[tid+off]; __syncthreads(); }
  float sm=red[0];
  if(tid<KPI){
    unsigned short v=0;
    if(tid<DIN){
      float alpha=e/sm;
      v=f2bf(xt[tid]*alpha+xt[tid]);
    }
    xi_b[(long)blk*KPI+tid]=v;
  }
}

// ---------- Gx[t][b][j] = xi @ W_ih^T + b_ih + b_hh (bf16 MFMA; W_ih fp32 read+cvt in regs) ----------
__global__ void __launch_bounds__(256) k_gx(const unsigned short* __restrict__ xi,
   const float* __restrict__ Wih, const float* __restrict__ b_ih,
   const float* __restrict__ b_hh, float* __restrict__ Gx){
  int w=threadIdx.x>>6, lane=threadIdx.x&63;
  int jt=blockIdx.x*4+w;
  if(jt>=NTILES) return;
  int j0=jt*32;
  int lj=lane&15, lk=lane>>4;
  short8 bfr[10][2];
  #pragma unroll
  for(int ks=0;ks<10;ks++)
    #pragma unroll
    for(int jh=0;jh<2;jh++){
      int j=j0+jh*16+lj;
      short8 bv;
      #pragma unroll
      for(int q=0;q<8;q++){
        int k=ks*32+lk*8+q;
        float f=(j<H4 && k<DIN)? Wih[(long)j*DIN+k] : 0.f;
        bv[q]=(short)f2bf(f);
      }
      bfr[ks][jh]=bv;
    }
  for(int t=0;t<TT;t++){
    f32x4 acc[2][2]={};
    #pragma unroll
    for(int ks=0;ks<10;ks++){
      #pragma unroll
      for(int mh=0;mh<2;mh++){
        short8 a=*(const short8*)(xi + ((long)(t*32+mh*16+lj))*KPI + ks*32 + lk*8);
        acc[mh][0]=mfma16(a,bfr[ks][0],acc[mh][0]);
        acc[mh][1]=mfma16(a,bfr[ks][1],acc[mh][1]);
      }
    }
    #pragma unroll
    for(int mh=0;mh<2;mh++)
      #pragma unroll
      for(int jh=0;jh<2;jh++){
        int j=j0+jh*16+lj;
        if(j<H4){
          float bias=b_ih[j]+b_hh[j];
          #pragma unroll
          for(int r=0;r<4;r++){
            int bb=mh*16+lk*4+r;     // C/D: col=lane&15, row=(lane>>4)*4+r  (m89-verified)
            Gx[((long)t*32+bb)*H4+j]=acc[mh][jh][r]+bias;
          }
        }
      }
  }
}

// ---------- fused LSTM step (bf16, pass 1 — unchanged from round 9) ----------
__global__ void __launch_bounds__(512) k_step(const unsigned short* __restrict__ hb_r,
    unsigned short* __restrict__ hb_w, const unsigned short* __restrict__ Whh,
    const float* __restrict__ Gx, const float* __restrict__ c0,
    float* __restrict__ c, float* __restrict__ hs, int t){
  const int tid=threadIdx.x;
  const int w=tid>>6, lane=tid&63;
  const int j0=blockIdx.x*16;
  const int lj=lane&15, lk=lane>>4;
  const int s0=(118*w)>>3, s1=(118*(w+1))>>3;
  const int jj=j0+lj;
  long rowb[4];
  #pragma unroll
  for(int g=0;g<4;g++) rowb[g]=(long)min(g*HID+jj, H4-1)*KP;
  f32x4 acc[4][2]={};
  #pragma unroll 2
  for(int ks=s0;ks<s1;ks++){
    int kofs=ks*32+lk*8;
    short8 a0=*(const short8*)(hb_r + (long)lj*KP + kofs);
    short8 a1=*(const short8*)(hb_r + (long)(16+lj)*KP + kofs);
    #pragma unroll
    for(int g=0;g<4;g++){
      short8 bv=*(const short8*)(Whh + rowb[g] + kofs);
      acc[g][0]=mfma16(a0,bv,acc[g][0]);
      acc[g][1]=mfma16(a1,bv,acc[g][1]);
    }
  }
  __shared__ float red[8][4][512];
  #pragma unroll
  for(int g=0;g<4;g++)
    #pragma unroll
    for(int mh=0;mh<2;mh++)
      #pragma unroll
      for(int r=0;r<4;r++)
        red[w][g][(mh*16+lk*4+r)*16+lj]=acc[g][mh][r];
  __syncthreads();
  if(tid<512){
    int p=tid;
    int bb=p>>4, jl=p&15; int j=j0+jl;
    if(j<HID){
      long gxo=((long)t*BSZ+bb)*H4 + j;
      float si=0,sf=0,sg=0,so=0;
      #pragma unroll
      for(int ww=0;ww<8;ww++){
        si+=red[ww][0][p]; sf+=red[ww][1][p];
        sg+=red[ww][2][p]; so+=red[ww][3][p];
      }
      si+=Gx[gxo]; sf+=Gx[gxo+HID]; sg+=Gx[gxo+2*HID]; so+=Gx[gxo+3*HID];
      float gi=sigm(si), gf=sigm(sf), gg=tanhf(sg), go=sigm(so);
      int idx=bb*HID+j;
      float cin=(t==0)?c0[idx]:c[idx];
      float c2=gf*cin+gi*gg;
      float h2=go*tanhf(c2);
      c[idx]=c2;
      hs[(long)t*BSZ*HID+idx]=h2;
      hb_w[(long)bb*KP+j]=f2bf(h2);
    }
  }
}

// ---------- fp8 PROBE step (pass 2, outputs to scratch, never read) ----------
__global__ void __launch_bounds__(512) k_step8(const unsigned char* __restrict__ hf_r,
    unsigned char* __restrict__ hf_w, const unsigned char* __restrict__ Wf8,
    const float* __restrict__ Gx, const float* __restrict__ c0,
    float* __restrict__ c2b, float* __restrict__ hs2, int t){
  const int tid=threadIdx.x;
  const int w=tid>>6, lane=tid&63;
  const int j0=blockIdx.x*16;
  const int lj=lane&15, lk=lane>>4;
  const int s0=(118*w)>>3, s1=(118*(w+1))>>3;
  const int jj=j0+lj;
  long rowb[4];
  #pragma unroll
  for(int g=0;g<4;g++) rowb[g]=(long)min(g*HID+jj, H4-1)*KP;
  f32x4 acc[4][2]={};
  #pragma unroll 2
  for(int ks=s0;ks<s1;ks++){
    int kofs=ks*32+lk*8;           // bytes (1 B/elem): 32 elems per kstep
    long a0=*(const long*)(hf_r + (long)lj*KP + kofs);
    long a1=*(const long*)(hf_r + (long)(16+lj)*KP + kofs);
    #pragma unroll
    for(int g=0;g<4;g++){
      long bv=*(const long*)(Wf8 + rowb[g] + kofs);
      acc[g][0]=mfma8(a0,bv,acc[g][0]);
      acc[g][1]=mfma8(a1,bv,acc[g][1]);
    }
  }
  __shared__ float red[8][4][512];
  #pragma unroll
  for(int g=0;g<4;g++)
    #pragma unroll
    for(int mh=0;mh<2;mh++)
      #pragma unroll
      for(int r=0;r<4;r++)
        red[w][g][(mh*16+lk*4+r)*16+lj]=acc[g][mh][r];
  __syncthreads();
  if(tid<512){
    int p=tid;
    int bb=p>>4, jl=p&15; int j=j0+jl;
    if(j<HID){
      long gxo=((long)t*BSZ+bb)*H4 + j;
      float si=0,sf=0,sg=0,so=0;
      #pragma unroll
      for(int ww=0;ww<8;ww++){
        si+=red[ww][0][p]; sf+=red[ww][1][p];
        sg+=red[ww][2][p]; so+=red[ww][3][p];
      }
      si=si*WINV+Gx[gxo]; sf=sf*WINV+Gx[gxo+HID];
      sg=sg*WINV+Gx[gxo+2*HID]; so=so*WINV+Gx[gxo+3*HID];
      float gi=sigm(si), gf=sigm(sf), gg=tanhf(sg), go=sigm(so);
      int idx=bb*HID+j;
      float cin=(t==0)?c0[idx]:c2b[idx];
      float cc=gf*cin+gi*gg;
      float h2=go*tanhf(cc);
      c2b[idx]=cc;
      hs2[(long)t*BSZ*HID+idx]=h2;
      hf_w[(long)bb*KP+j]=f2e4m3(h2);
    }
  }
}

// ---------- fused tail: beta softmax + weighted output ----------
__global__ void k_tail(const float* __restrict__ hs, const float* __restrict__ ta2_w,
   const float* __restrict__ ta2_b, const float* __restrict__ x_in,
   const float* __restrict__ out_w, const float* __restrict__ out_b,
   float* __restrict__ out0){
  int b=blockIdx.x, tid=threadIdx.x;
  float p[12]={0,0,0,0,0,0,0,0,0,0,0,0};
  for(int idx=tid; idx<TT*HID; idx+=256){
    int t=idx/HID, j=idx-t*HID;
    float v=hs[((long)t*BSZ+b)*HID+j];
    #pragma unroll
    for(int q=0;q<12;q++) p[q]+=v*ta2_w[(long)q*TT*HID+idx];
  }
  __shared__ float red[256];
  __shared__ float bt[12];
  float z[12];
  #pragma unroll
  for(int q=0;q<12;q++){
    __syncthreads();
    red[tid]=p[q]; __syncthreads();
    for(int off=128;off>0;off>>=1){ if(tid<off) red[tid]+=red[tid+off]; __syncthreads(); }
    z[q]=red[0];
  }
  if(tid==0){
    float mx=-1e30f;
    #pragma unroll
    for(int q=0;q<12;q++){ z[q]=fmaxf(z[q]+ta2_b[q],0.f); mx=fmaxf(mx,z[q]); }
    float sm=0;
    #pragma unroll
    for(int q=0;q<12;q++){ z[q]=__expf(z[q]-mx); sm+=z[q]; }
    #pragma unroll
    for(int q=0;q<12;q++) bt[q]=z[q]/sm;
  }
  __syncthreads();
  float acc=0;
  for(int j=tid;j<HID;j+=256){
    float ov=0;
    #pragma unroll
    for(int t=0;t<TT;t++) ov+=hs[((long)t*BSZ+b)*HID+j]*bt[t];
    ov+=x_in[(long)b*HID+j];
    acc+=fmaxf(ov,0.f)*out_w[j];
  }
  __syncthreads();
  red[tid]=acc; __syncthreads();
  for(int off=128;off>0;off>>=1){ if(tid<off) red[tid]+=red[tid+off]; __syncthreads(); }
  if(tid==0) out0[b]=red[0]+out_b[0];
}

extern "C" void kernel_launch(void* const* d_in, const int* in_sizes, int n_in,
                              void* d_out, int out_size, void* d_ws, size_t ws_size,
                              hipStream_t stream){
  (void)in_sizes; (void)n_in; (void)out_size; (void)ws_size;
  const float* X     =(const float*)d_in[0];
  const float* cheb  =(const float*)d_in[1];
  const float* sa_W1 =(const float*)d_in[2];
  const float* sa_W2 =(const float*)d_in[3];
  const float* sa_W3 =(const float*)d_in[4];
  const float* sa_bs =(const float*)d_in[5];
  const float* sa_Vs =(const float*)d_in[6];
  const float* ta_U1 =(const float*)d_in[7];
  const float* ta_U2 =(const float*)d_in[8];
  const float* ta_U3 =(const float*)d_in[9];
  const float* ta_be =(const float*)d_in[10];
  const float* ta_Ve =(const float*)d_in[11];
  const float* theta =(const float*)d_in[12];
  const float* cb    =(const float*)d_in[13];
  const float* ln_g  =(const float*)d_in[14];
  const float* ln_b  =(const float*)d_in[15];
  const float* liw   =(const float*)d_in[16];
  const float* lib   =(const float*)d_in[17];
  const float* sa2_w =(const float*)d_in[18];
  const float* sa2_b =(const float*)d_in[19];
  const float* W_ih  =(const float*)d_in[20];
  const float* W_hh  =(const float*)d_in[21];
  const float* b_ih  =(const float*)d_in[22];
  const float* b_hh  =(const float*)d_in[23];
  const float* ta2_w =(const float*)d_in[24];
  const float* ta2_b =(const float*)d_in[25];
  const float* out_w =(const float*)d_in[26];
  const float* out_b =(const float*)d_in[27];
  const float* h0    =(const float*)d_in[28];
  const float* c0    =(const float*)d_in[29];

  char* w=(char*)d_ws;
  unsigned short* Whh_b=(unsigned short*)(w);                 // 113,461,248
  float* Gx   =(float*)(w+113461248);                         // 23,076,864 -> 136,538,112
  float* hs   =(float*)(w+136538112);                         //  5,769,216 -> 142,307,328
  unsigned short* hb0=(unsigned short*)(w+142307328);         //    241,664 -> 142,548,992
  unsigned short* hb1=(unsigned short*)(w+142548992);         //    241,664 -> 142,790,656
  float* c    =(float*)(w+142790656);                         //    480,768 -> 143,271,424
  float* x_in =(float*)(w+143271424);                         //    480,768 -> 143,752,192
  unsigned short* xi_b=(unsigned short*)(w+143752192);        //    245,760 -> 143,997,952
  float* SA   =(float*)(w+143997952);                         //     73,728
  float* TA   =(float*)(w+144071680);                         //     18,432
  float* s_a  =(float*)(w+144090112);                         //     73,728
  float* t_a  =(float*)(w+144163840);                         //     18,432 -> 144,182,272
  unsigned char* Wf8 =(unsigned char*)(w+144182272);          // 56,730,624 -> 200,912,896
  unsigned char* hf80=(unsigned char*)(w+200912896);          //    120,832 -> 201,033,728
  unsigned char* hf81=(unsigned char*)(w+201033728);          //    120,832 -> 201,154,560
  float* c2   =(float*)(w+201154560);                         //    480,768 -> 201,635,328
  float* hs2  =(float*)(w+201635328);                         //  5,769,216 -> 207,404,544
  float* out_f=(float*)d_out;                                 // [0..31]=out, [32..]=s_a

  k_convall<<<2048,256,0,stream>>>(W_hh,h0,Whh_b,hb0,hb1,Wf8,hf80,hf81);
  k_attn<<<32,256,0,stream>>>(X,sa_W1,sa_W2,sa_W3,sa_bs,sa_Vs,ta_U1,ta_U2,ta_U3,ta_be,ta_Ve,SA,TA);
  k_bsoftmax<<<3,256,0,stream>>>(SA,TA,s_a,t_a,out_f+32);
  k_graph<<<32,320,0,stream>>>(X,cheb,s_a,t_a,theta,cb,ln_g,ln_b,liw,lib,x_in);
  k_alpha<<<384,512,0,stream>>>(x_in,sa2_w,sa2_b,xi_b);
  k_gx<<<118,256,0,stream>>>(xi_b,W_ih,b_ih,b_hh,Gx);
  unsigned short* hb[2]={hb0,hb1};
  for(int t=0;t<TT;t++)
    k_step<<<NB,512,0,stream>>>(hb[t&1],hb[(t+1)&1],Whh_b,Gx,c0,c,hs,t);
  k_tail<<<32,256,0,stream>>>(hs,ta2_w,ta2_b,x_in,out_w,out_b,out_f);
  // ---- fp8 speed PROBE (outputs discarded; measures 12 x s_fp8 in dur delta) ----
  unsigned char* hf[2]={hf80,hf81};
  for(int t=0;t<TT;t++)
    k_step8<<<NB,512,0,stream>>>(hf[t&1],hf[(t+1)&1],Wf8,Gx,c0,c2,hs2,t);
}

// Round 11
// 687.394 us; speedup vs baseline: 1.2726x; 1.2726x over previous
//
#include <hip/hip_runtime.h>

#define BSZ 32
#define NN 24
#define TT 12
#define FF 3
#define KK 3
#define COUT 12
#define DIN 313          // N*COUT + N + 1
#define HID 3756         // DIN*T
#define H4 15024         // 4*HID
#define KP 3776          // HID padded to 118*32
#define KPI 320          // DIN padded to 10*32
#define NTILES 470       // ceil(15024/32)
#define NB 235           // ceil(3756/16) j-tiles for fused step

using short8 = __attribute__((ext_vector_type(8))) short;
using f32x4  = __attribute__((ext_vector_type(4))) float;

__device__ inline unsigned short f2bf(float f){
  union{float f; unsigned u;} v; v.f=f;
  unsigned u=v.u;
  return (unsigned short)((u + 0x7FFFu + ((u>>16)&1u))>>16);
}
__device__ inline f32x4 mfma16(short8 a, short8 b, f32x4 c){
  return __builtin_amdgcn_mfma_f32_16x16x32_bf16(a,b,c,0,0,0);
}
__device__ inline float sigm(float x){ return 1.f/(1.f+expf(-x)); }

// ---------- fused conversion: W_hh fp32 -> bf16 PACKED per-block slabs; h0 -> bf16 ----------
// Packed layout: Wp[bi][ks][g][lane][8elems]; lane l holds W[g*HID + bi*16 + (l&15)]
// [ks*32 + (l>>4)*8 .. +8] — byte-identical per-lane data to the old strided load,
// but every wave load is one contiguous 1KB chunk and each block owns a contiguous slab.
__global__ void k_convpack(const float* __restrict__ W, const float* __restrict__ h0f,
    unsigned short* __restrict__ Wp, unsigned short* __restrict__ hb0,
    unsigned short* __restrict__ hb1){
  const long stride=(long)gridDim.x*blockDim.x;
  const long tid0=(long)blockIdx.x*blockDim.x+threadIdx.x;
  const long totalW=(long)NB*118*4*64;          // 16B units
  for(long u=tid0; u<totalW; u+=stride){
    int l=(int)(u&63);
    long v=u>>6;
    int g=(int)(v&3); v>>=2;
    int ks=(int)(v%118);
    int bi=(int)(v/118);
    int lj=l&15, lk=l>>4;
    int jj=bi*16+lj; if(jj>=HID) jj=HID-1;
    int row=g*HID+jj;
    int k0=ks*32+lk*8;
    const float* src=W+(long)row*HID;
    short8 o;
    #pragma unroll
    for(int q=0;q<8;q++){
      int k=k0+q;
      o[q]=(k<HID)?(short)f2bf(src[k]):(short)0;
    }
    *(short8*)(Wp + u*8) = o;
  }
  const int g4=KP>>2;
  const int totalH=BSZ*g4;
  for(long i=tid0; i<totalH; i+=stride){
    int gq=(int)(i%g4), r=(int)(i/g4);
    int k=gq*4;
    float vv[4];
    if(k+3<HID){
      float4 x=*(const float4*)(h0f+(long)r*HID+k);
      vv[0]=x.x; vv[1]=x.y; vv[2]=x.z; vv[3]=x.w;
    } else {
      #pragma unroll
      for(int q=0;q<4;q++){ int kk=k+q; vv[q]=(kk<HID)? h0f[(long)r*HID+kk] : 0.f; }
    }
    ushort4 o;
    o.x=f2bf(vv[0]); o.y=f2bf(vv[1]); o.z=f2bf(vv[2]); o.w=f2bf(vv[3]);
    *(ushort4*)(hb0+(long)r*KP+k)=o;
    *(ushort4*)(hb1+(long)r*KP+k)=o;
  }
}

// ---------- spatial + temporal attention (pre batch-softmax), per batch ----------
__global__ void k_attn(const float* __restrict__ X, const float* __restrict__ sa_W1,
   const float* __restrict__ sa_W2, const float* __restrict__ sa_W3,
   const float* __restrict__ sa_bs, const float* __restrict__ sa_Vs,
   const float* __restrict__ ta_U1, const float* __restrict__ ta_U2,
   const float* __restrict__ ta_U3, const float* __restrict__ ta_be,
   const float* __restrict__ ta_Ve,
   float* __restrict__ SA_pre, float* __restrict__ TA_pre){
  int b=blockIdx.x, tid=threadIdx.x;
  __shared__ float lin[864];            // raw X[b], layout [n][t][f]
  __shared__ float lhs[NN*TT];
  __shared__ float rhs[TT*NN];
  __shared__ float P[NN*NN];
  __shared__ float S[NN*NN];
  __shared__ float lhsT[TT*NN];
  __shared__ float rhsT[NN*TT];
  __shared__ float PT[TT*TT];
  __shared__ float E[TT*TT];
  for(int i=tid;i<864;i+=256) lin[i]=X[b*864+i];
  __syncthreads();
  for(int i=tid;i<NN*TT;i+=256){ int n=i/TT, t=i%TT;
    float acc=0;
    #pragma unroll
    for(int f=0;f<FF;f++){
      float t1=0;
      for(int u=0;u<TT;u++) t1 += lin[n*36+u*3+f]*sa_W1[u];
      acc += t1*sa_W2[f*TT+t];
    }
    lhs[n*TT+t]=acc;
    float r=0;
    #pragma unroll
    for(int f=0;f<FF;f++) r += sa_W3[f]*lin[n*36+t*3+f];
    rhs[t*NN+n]=r;
  }
  for(int i=tid;i<TT*NN;i+=256){ int t=i/NN, n=i%NN;
    float acc=0;
    #pragma unroll
    for(int f=0;f<FF;f++){
      float t1=0;
      for(int m=0;m<NN;m++) t1 += lin[m*36+t*3+f]*ta_U1[m];
      acc += t1*ta_U2[f*NN+n];
    }
    lhsT[t*NN+n]=acc;
    float r=0;
    #pragma unroll
    for(int f=0;f<FF;f++) r += ta_U3[f]*lin[n*36+t*3+f];
    rhsT[n*TT+t]=r;
  }
  __syncthreads();
  for(int i=tid;i<NN*NN;i+=256){ int n=i/NN,m=i%NN;
    float a=0;
    for(int t=0;t<TT;t++) a+=lhs[n*TT+t]*rhs[t*NN+m];
    P[i]=sigm(a+sa_bs[i]);
  }
  for(int i=tid;i<TT*TT;i+=256){ int t=i/TT,u=i%TT;
    float a=0;
    for(int n=0;n<NN;n++) a+=lhsT[t*NN+n]*rhsT[n*TT+u];
    PT[i]=sigm(a+ta_be[i]);
  }
  __syncthreads();
  for(int i=tid;i<NN*NN;i+=256){ int n=i/NN,k=i%NN;
    float a=0;
    for(int m=0;m<NN;m++) a+=sa_Vs[n*NN+m]*P[m*NN+k];
    S[i]=a;
  }
  for(int i=tid;i<TT*TT;i+=256){ int t=i/TT,v=i%TT;
    float a=0;
    for(int u=0;u<TT;u++) a+=ta_Ve[t*TT+u]*PT[u*TT+v];
    E[i]=a;
  }
  __syncthreads();
  if(tid<NN){ int k=tid;
    float mx=-1e30f;
    for(int n=0;n<NN;n++) mx=fmaxf(mx,S[n*NN+k]);
    float sm=0;
    for(int n=0;n<NN;n++) sm+=__expf(S[n*NN+k]-mx);
    for(int n=0;n<NN;n++){
      float v=__expf(S[n*NN+k]-mx)/sm;
      SA_pre[b*576+n*NN+k]=sigm(v);
    }
  }
  if(tid>=32 && tid<32+TT){ int v=tid-32;
    float mx=-1e30f;
    for(int t=0;t<TT;t++) mx=fmaxf(mx,E[t*TT+v]);
    float sm=0;
    for(int t=0;t<TT;t++) sm+=__expf(E[t*TT+v]-mx);
    for(int t=0;t<TT;t++){
      float e=__expf(E[t*TT+v]-mx)/sm;
      TA_pre[b*144+t*TT+v]=sigm(e);
    }
  }
}

// ---------- softmax over batch axis; s_a also written to OUTPUT as float ----------
__global__ void k_bsoftmax(const float* __restrict__ SA_pre, const float* __restrict__ TA_pre,
    float* __restrict__ s_a, float* __restrict__ t_a, float* __restrict__ out_sa){
  int i=blockIdx.x*blockDim.x+threadIdx.x;
  if(i<576){
    float mx=-1e30f;
    for(int b=0;b<BSZ;b++) mx=fmaxf(mx,SA_pre[b*576+i]);
    float sm=0;
    for(int b=0;b<BSZ;b++) sm+=__expf(SA_pre[b*576+i]-mx);
    for(int b=0;b<BSZ;b++){
      float v=__expf(SA_pre[b*576+i]-mx)/sm;
      s_a[b*576+i]=v;
      out_sa[b*576+i]=v;
    }
  } else if(i<720){
    int j=i-576;
    float mx=-1e30f;
    for(int b=0;b<BSZ;b++) mx=fmaxf(mx,TA_pre[b*144+j]);
    float sm=0;
    for(int b=0;b<BSZ;b++) sm+=__expf(TA_pre[b*144+j]-mx);
    for(int b=0;b<BSZ;b++) t_a[b*144+j]=__expf(TA_pre[b*144+j]-mx)/sm;
  }
}

// ---------- graph conv + LN + temporal mix + input layer, per batch ----------
__global__ void k_graph(const float* __restrict__ X, const float* __restrict__ cheb,
  const float* __restrict__ s_a, const float* __restrict__ t_a,
  const float* __restrict__ theta, const float* __restrict__ cheb_bias,
  const float* __restrict__ ln_g, const float* __restrict__ ln_b,
  const float* __restrict__ liw, const float* __restrict__ lib,
  float* __restrict__ x_in){
  int b=blockIdx.x, tid=threadIdx.x;
  __shared__ float lin[864];
  __shared__ float A2[KK*NN*NN];
  __shared__ float rg[KK*NN*FF*TT];
  __shared__ float xc[NN*COUT*TT];
  __shared__ float xres[DIN*TT];
  __shared__ float ta_s[TT*TT];
  for(int i=tid;i<864;i+=320) lin[i]=X[b*864+i];
  for(int i=tid;i<KK*NN*NN;i+=320){ int mn=i%576; A2[i]=cheb[i]*s_a[b*576+mn]; }
  for(int i=tid;i<144;i+=320) ta_s[i]=t_a[b*144+i];
  __syncthreads();
  for(int i=tid;i<KK*NN*FF*TT;i+=320){
    int t=i%TT, f=(i/TT)%FF, n=(i/36)%NN, k=i/864;
    float a=0;
    for(int m=0;m<NN;m++) a+=A2[k*576+m*NN+n]*lin[m*36+f*TT+t];
    rg[i]=a;
  }
  __syncthreads();
  for(int i=tid;i<NN*COUT*TT;i+=320){
    int t=i%TT, o=(i/TT)%COUT, n=i/(COUT*TT);
    float a=cheb_bias[o];
    #pragma unroll
    for(int k=0;k<KK;k++)
      #pragma unroll
      for(int f=0;f<FF;f++)
        a += rg[((k*NN+n)*FF+f)*TT+t]*theta[(k*FF+f)*COUT+o];
    xc[i]=fmaxf(a,0.f);
  }
  __syncthreads();
  if(tid<NN*COUT){
    float mu=0;
    for(int t=0;t<TT;t++) mu+=xc[tid*TT+t];
    mu*=(1.f/12.f);
    float var=0;
    for(int t=0;t<TT;t++){ float d=xc[tid*TT+t]-mu; var+=d*d; }
    var*=(1.f/12.f);
    float inv=rsqrtf(var+1e-5f);
    for(int t=0;t<TT;t++) xc[tid*TT+t]=(xc[tid*TT+t]-mu)*inv*ln_g[t]+ln_b[t];
  }
  __syncthreads();
  for(int i=tid;i<NN*COUT;i+=320){
    for(int v=0;v<TT;v++){
      float a=0;
      for(int t=0;t<TT;t++) a+=xc[i*TT+t]*ta_s[t*TT+v];
      xres[i*TT+v]=a;
    }
  }
  for(int i=tid;i<25*TT;i+=320){
    int r=i/TT, t=i%TT;
    float v=(r<NN)? lin[r*36+t*3+0] : lin[t*3+1];
    xres[(288+r)*TT+t]=v;
  }
  __syncthreads();
  for(int i=tid;i<DIN;i+=320){
    for(int t=0;t<TT;t++){
      float a=lib[t];
      #pragma unroll
      for(int u=0;u<TT;u++) a+=xres[i*TT+u]*liw[t*TT+u];
      x_in[((long)b*DIN+i)*TT+t]=a;
    }
  }
}

// ---------- per-(t,b): alpha softmax gate, xi -> bf16 padded [t*32+b][KPI] ----------
__global__ void __launch_bounds__(512) k_alpha(const float* __restrict__ x_in,
    const float* __restrict__ sa2_w, const float* __restrict__ sa2_b,
    unsigned short* __restrict__ xi_b){
  int blk=blockIdx.x; int t=blk>>5, b=blk&31; int tid=threadIdx.x;
  __shared__ float xt[DIN];
  __shared__ float red[512];
  if(tid<DIN) xt[tid]=x_in[((long)b*DIN+tid)*TT+t];
  __syncthreads();
  float z=-1e30f, e=0.f;
  if(tid<DIN){
    float a=sa2_b[tid];
    const float* wr=sa2_w+(long)tid*DIN;
    for(int i=0;i<DIN;i++) a+=xt[i]*wr[i];
    z=sigm(a);
  }
  red[tid]=z; __syncthreads();
  for(int off=256;off>0;off>>=1){ if(tid<off) red[tid]=fmaxf(red[tid],red[tid+off]); __syncthreads(); }
  float mx=red[0]; __syncthreads();
  e=(tid<DIN)?__expf(z-mx):0.f;
  red[tid]=e; __syncthreads();
  for(int off=256;off>0;off>>=1){ if(tid<off) red[tid]+=red[tid+off]; __syncthreads(); }
  float sm=red[0];
  if(tid<KPI){
    unsigned short v=0;
    if(tid<DIN){
      float alpha=e/sm;
      v=f2bf(xt[tid]*alpha+xt[tid]);
    }
    xi_b[(long)blk*KPI+tid]=v;
  }
}

// ---------- Gx[t][b][j] = xi @ W_ih^T + b_ih + b_hh (bf16 MFMA; W_ih fp32 read+cvt in regs) ----------
__global__ void __launch_bounds__(256) k_gx(const unsigned short* __restrict__ xi,
   const float* __restrict__ Wih, const float* __restrict__ b_ih,
   const float* __restrict__ b_hh, float* __restrict__ Gx){
  int w=threadIdx.x>>6, lane=threadIdx.x&63;
  int jt=blockIdx.x*4+w;
  if(jt>=NTILES) return;
  int j0=jt*32;
  int lj=lane&15, lk=lane>>4;
  short8 bfr[10][2];
  #pragma unroll
  for(int ks=0;ks<10;ks++)
    #pragma unroll
    for(int jh=0;jh<2;jh++){
      int j=j0+jh*16+lj;
      short8 bv;
      #pragma unroll
      for(int q=0;q<8;q++){
        int k=ks*32+lk*8+q;
        float f=(j<H4 && k<DIN)? Wih[(long)j*DIN+k] : 0.f;
        bv[q]=(short)f2bf(f);
      }
      bfr[ks][jh]=bv;
    }
  for(int t=0;t<TT;t++){
    f32x4 acc[2][2]={};
    #pragma unroll
    for(int ks=0;ks<10;ks++){
      #pragma unroll
      for(int mh=0;mh<2;mh++){
        short8 a=*(const short8*)(xi + ((long)(t*32+mh*16+lj))*KPI + ks*32 + lk*8);
        acc[mh][0]=mfma16(a,bfr[ks][0],acc[mh][0]);
        acc[mh][1]=mfma16(a,bfr[ks][1],acc[mh][1]);
      }
    }
    #pragma unroll
    for(int mh=0;mh<2;mh++)
      #pragma unroll
      for(int jh=0;jh<2;jh++){
        int j=j0+jh*16+lj;
        if(j<H4){
          float bias=b_ih[j]+b_hh[j];
          #pragma unroll
          for(int r=0;r<4;r++){
            int bb=mh*16+lk*4+r;     // C/D: col=lane&15, row=(lane>>4)*4+r  (m89-verified)
            Gx[((long)t*32+bb)*H4+j]=acc[mh][jh][r]+bias;
          }
        }
      }
  }
}

// ---------- fused LSTM step (bf16, PACKED W slabs: contiguous 1KB loads) ----------
__global__ void __launch_bounds__(512) k_step(const unsigned short* __restrict__ hb_r,
    unsigned short* __restrict__ hb_w, const unsigned short* __restrict__ Wp,
    const float* __restrict__ Gx, const float* __restrict__ c0,
    float* __restrict__ c, float* __restrict__ hs, int t){
  const int tid=threadIdx.x;
  const int w=tid>>6, lane=tid&63;
  const int j0=blockIdx.x*16;
  const int lj=lane&15, lk=lane>>4;
  const int s0=(118*w)>>3, s1=(118*(w+1))>>3;
  const unsigned short* slab = Wp + (long)blockIdx.x*64*KP;  // contiguous 483KB per block
  f32x4 acc[4][2]={};
  #pragma unroll 2
  for(int ks=s0;ks<s1;ks++){
    int kofs=ks*32+lk*8;
    short8 a0=*(const short8*)(hb_r + (long)lj*KP + kofs);
    short8 a1=*(const short8*)(hb_r + (long)(16+lj)*KP + kofs);
    const unsigned short* pk = slab + ((long)ks<<11);        // ks*4gates*512
    #pragma unroll
    for(int g=0;g<4;g++){
      short8 bv=*(const short8*)(pk + (g<<9) + (lane<<3));   // contiguous 1KB per wave-load
      acc[g][0]=mfma16(a0,bv,acc[g][0]);
      acc[g][1]=mfma16(a1,bv,acc[g][1]);
    }
  }
  __shared__ float red[8][4][512];
  #pragma unroll
  for(int g=0;g<4;g++)
    #pragma unroll
    for(int mh=0;mh<2;mh++)
      #pragma unroll
      for(int r=0;r<4;r++)
        red[w][g][(mh*16+lk*4+r)*16+lj]=acc[g][mh][r];
  __syncthreads();
  if(tid<512){
    int p=tid;
    int bb=p>>4, jl=p&15; int j=j0+jl;
    if(j<HID){
      long gxo=((long)t*BSZ+bb)*H4 + j;
      float si=0,sf=0,sg=0,so=0;
      #pragma unroll
      for(int ww=0;ww<8;ww++){
        si+=red[ww][0][p]; sf+=red[ww][1][p];
        sg+=red[ww][2][p]; so+=red[ww][3][p];
      }
      si+=Gx[gxo]; sf+=Gx[gxo+HID]; sg+=Gx[gxo+2*HID]; so+=Gx[gxo+3*HID];
      float gi=sigm(si), gf=sigm(sf), gg=tanhf(sg), go=sigm(so);
      int idx=bb*HID+j;
      float cin=(t==0)?c0[idx]:c[idx];
      float c2=gf*cin+gi*gg;
      float h2=go*tanhf(c2);
      c[idx]=c2;
      hs[(long)t*BSZ*HID+idx]=h2;
      hb_w[(long)bb*KP+j]=f2bf(h2);
    }
  }
}

// ---------- fused tail: beta softmax + weighted output ----------
__global__ void k_tail(const float* __restrict__ hs, const float* __restrict__ ta2_w,
   const float* __restrict__ ta2_b, const float* __restrict__ x_in,
   const float* __restrict__ out_w, const float* __restrict__ out_b,
   float* __restrict__ out0){
  int b=blockIdx.x, tid=threadIdx.x;
  float p[12]={0,0,0,0,0,0,0,0,0,0,0,0};
  for(int idx=tid; idx<TT*HID; idx+=256){
    int t=idx/HID, j=idx-t*HID;
    float v=hs[((long)t*BSZ+b)*HID+j];
    #pragma unroll
    for(int q=0;q<12;q++) p[q]+=v*ta2_w[(long)q*TT*HID+idx];
  }
  __shared__ float red[256];
  __shared__ float bt[12];
  float z[12];
  #pragma unroll
  for(int q=0;q<12;q++){
    __syncthreads();
    red[tid]=p[q]; __syncthreads();
    for(int off=128;off>0;off>>=1){ if(tid<off) red[tid]+=red[tid+off]; __syncthreads(); }
    z[q]=red[0];
  }
  if(tid==0){
    float mx=-1e30f;
    #pragma unroll
    for(int q=0;q<12;q++){ z[q]=fmaxf(z[q]+ta2_b[q],0.f); mx=fmaxf(mx,z[q]); }
    float sm=0;
    #pragma unroll
    for(int q=0;q<12;q++){ z[q]=__expf(z[q]-mx); sm+=z[q]; }
    #pragma unroll
    for(int q=0;q<12;q++) bt[q]=z[q]/sm;
  }
  __syncthreads();
  float acc=0;
  for(int j=tid;j<HID;j+=256){
    float ov=0;
    #pragma unroll
    for(int t=0;t<TT;t++) ov+=hs[((long)t*BSZ+b)*HID+j]*bt[t];
    ov+=x_in[(long)b*HID+j];
    acc+=fmaxf(ov,0.f)*out_w[j];
  }
  __syncthreads();
  red[tid]=acc; __syncthreads();
  for(int off=128;off>0;off>>=1){ if(tid<off) red[tid]+=red[tid+off]; __syncthreads(); }
  if(tid==0) out0[b]=red[0]+out_b[0];
}

extern "C" void kernel_launch(void* const* d_in, const int* in_sizes, int n_in,
                              void* d_out, int out_size, void* d_ws, size_t ws_size,
                              hipStream_t stream){
  (void)in_sizes; (void)n_in; (void)out_size; (void)ws_size;
  const float* X     =(const float*)d_in[0];
  const float* cheb  =(const float*)d_in[1];
  const float* sa_W1 =(const float*)d_in[2];
  const float* sa_W2 =(const float*)d_in[3];
  const float* sa_W3 =(const float*)d_in[4];
  const float* sa_bs =(const float*)d_in[5];
  const float* sa_Vs =(const float*)d_in[6];
  const float* ta_U1 =(const float*)d_in[7];
  const float* ta_U2 =(const float*)d_in[8];
  const float* ta_U3 =(const float*)d_in[9];
  const float* ta_be =(const float*)d_in[10];
  const float* ta_Ve =(const float*)d_in[11];
  const float* theta =(const float*)d_in[12];
  const float* cb    =(const float*)d_in[13];
  const float* ln_g  =(const float*)d_in[14];
  const float* ln_b  =(const float*)d_in[15];
  const float* liw   =(const float*)d_in[16];
  const float* lib   =(const float*)d_in[17];
  const float* sa2_w =(const float*)d_in[18];
  const float* sa2_b =(const float*)d_in[19];
  const float* W_ih  =(const float*)d_in[20];
  const float* W_hh  =(const float*)d_in[21];
  const float* b_ih  =(const float*)d_in[22];
  const float* b_hh  =(const float*)d_in[23];
  const float* ta2_w =(const float*)d_in[24];
  const float* ta2_b =(const float*)d_in[25];
  const float* out_w =(const float*)d_in[26];
  const float* out_b =(const float*)d_in[27];
  const float* h0    =(const float*)d_in[28];
  const float* c0    =(const float*)d_in[29];

  char* w=(char*)d_ws;
  unsigned short* Wp =(unsigned short*)(w);                   // NB*64*KP*2 = 113,582,080
  float* Gx   =(float*)(w+113582080);                         // 23,076,864 -> 136,658,944
  float* hs   =(float*)(w+136658944);                         //  5,769,216 -> 142,428,160
  unsigned short* hb0=(unsigned short*)(w+142428160);         //    241,664 -> 142,669,824
  unsigned short* hb1=(unsigned short*)(w+142669824);         //    241,664 -> 142,911,488
  float* c    =(float*)(w+142911488);                         //    480,768 -> 143,392,256
  float* x_in =(float*)(w+143392256);                         //    480,768 -> 143,873,024
  unsigned short* xi_b=(unsigned short*)(w+143873024);        //    245,760 -> 144,118,784
  float* SA   =(float*)(w+144118784);                         //     73,728
  float* TA   =(float*)(w+144192512);                         //     18,432
  float* s_a  =(float*)(w+144210944);                         //     73,728
  float* t_a  =(float*)(w+144284672);                         //     18,432
  float* out_f=(float*)d_out;                                 // [0..31]=out, [32..]=s_a

  k_convpack<<<2048,256,0,stream>>>(W_hh,h0,Wp,hb0,hb1);
  k_attn<<<32,256,0,stream>>>(X,sa_W1,sa_W2,sa_W3,sa_bs,sa_Vs,ta_U1,ta_U2,ta_U3,ta_be,ta_Ve,SA,TA);
  k_bsoftmax<<<3,256,0,stream>>>(SA,TA,s_a,t_a,out_f+32);
  k_graph<<<32,320,0,stream>>>(X,cheb,s_a,t_a,theta,cb,ln_g,ln_b,liw,lib,x_in);
  k_alpha<<<384,512,0,stream>>>(x_in,sa2_w,sa2_b,xi_b);
  k_gx<<<118,256,0,stream>>>(xi_b,W_ih,b_ih,b_hh,Gx);
  unsigned short* hb[2]={hb0,hb1};
  for(int t=0;t<TT;t++)
    k_step<<<NB,512,0,stream>>>(hb[t&1],hb[(t+1)&1],Wp,Gx,c0,c,hs,t);
  k_tail<<<32,256,0,stream>>>(hs,ta2_w,ta2_b,x_in,out_w,out_b,out_f);
}

// Round 12
// 577.436 us; speedup vs baseline: 1.5149x; 1.1904x over previous
//
#include <hip/hip_runtime.h>

#define BSZ 32
#define NN 24
#define TT 12
#define FF 3
#define KK 3
#define COUT 12
#define DIN 313          // N*COUT + N + 1
#define HID 3756         // DIN*T
#define H4 15024         // 4*HID
#define KP 3776          // HID padded to 118*32
#define KPI 320          // DIN padded to 10*32
#define NTILES 470       // ceil(15024/32)
#define NB 235           // ceil(3756/16) j-tiles for fused step
#define NCH 30           // K chunk-groups of 4 ks (29x4 + 1x2 = 118)

using short8 = __attribute__((ext_vector_type(8))) short;
using f32x4  = __attribute__((ext_vector_type(4))) float;

__device__ inline unsigned short f2bf(float f){
  union{float f; unsigned u;} v; v.f=f;
  unsigned u=v.u;
  return (unsigned short)((u + 0x7FFFu + ((u>>16)&1u))>>16);
}
__device__ inline f32x4 mfma16(short8 a, short8 b, f32x4 c){
  return __builtin_amdgcn_mfma_f32_16x16x32_bf16(a,b,c,0,0,0);
}
__device__ inline float sigm(float x){ return 1.f/(1.f+expf(-x)); }

// ---------- W_hh fp32 -> bf16 PACKED slabs, both-side coalesced via LDS transpose ----------
// Packed layout (unchanged from round 11): unit u = ((bi*118+ks)*4+g)*64 + l holds
// W[g*HID + bi*16 + (l&15)][ks*32 + (l>>4)*8 .. +8] as short8.
__global__ void __launch_bounds__(256) k_convpack(const float* __restrict__ W,
    unsigned short* __restrict__ Wp){
  __shared__ unsigned short lds[64*136];          // 64 rows x 128 k (+8 pad) ushorts
  const int bi=blockIdx.x, cz=blockIdx.y, tid=threadIdx.x;
  for(int cg=cz; cg<NCH; cg+=6){
    int ks0=cg*4;
    int nks=min(4,118-ks0);
    int nf4=nks*8;                                // float4 per row this chunk
    for(int q=tid;q<64*nf4;q+=256){
      int r=q/nf4, f4=q-r*nf4;
      int g=r>>4, lj=r&15;
      int jj=bi*16+lj; if(jj>=HID) jj=HID-1;
      const float* src=W+(long)(g*HID+jj)*HID;
      int k=ks0*32+f4*4;
      ushort4 o;
      if(k+3<HID){
        float4 v=*(const float4*)(src+k);
        o.x=f2bf(v.x); o.y=f2bf(v.y); o.z=f2bf(v.z); o.w=f2bf(v.w);
      } else {
        float vv[4];
        #pragma unroll
        for(int t2=0;t2<4;t2++){ int kk=k+t2; vv[t2]=(kk<HID)?src[kk]:0.f; }
        o.x=f2bf(vv[0]); o.y=f2bf(vv[1]); o.z=f2bf(vv[2]); o.w=f2bf(vv[3]);
      }
      *(ushort4*)(&lds[r*136+f4*4])=o;
    }
    __syncthreads();
    for(int idx=tid; idx<nks*4*64; idx+=256){
      int l=idx&63, g=(idx>>6)&3, kl=idx>>8;
      int lj=l&15, lk=l>>4;
      short8 v=*(short8*)(&lds[(g*16+lj)*136 + kl*32 + lk*8]);
      *(short8*)(Wp + (((long)(bi*118+ks0+kl)*4+g)*64 + l)*8) = v;
    }
    __syncthreads();
  }
}

// ---------- h0 -> bf16 ping+pong buffers ----------
__global__ void k_convh(const float* __restrict__ h0f,
    unsigned short* __restrict__ hb0, unsigned short* __restrict__ hb1){
  const int g4=KP>>2;
  const int total=BSZ*g4;
  for(int i=blockIdx.x*blockDim.x+threadIdx.x; i<total; i+=gridDim.x*blockDim.x){
    int gq=i%g4, r=i/g4;
    int k=gq*4;
    float vv[4];
    if(k+3<HID){
      float4 x=*(const float4*)(h0f+(long)r*HID+k);
      vv[0]=x.x; vv[1]=x.y; vv[2]=x.z; vv[3]=x.w;
    } else {
      #pragma unroll
      for(int q=0;q<4;q++){ int kk=k+q; vv[q]=(kk<HID)? h0f[(long)r*HID+kk] : 0.f; }
    }
    ushort4 o;
    o.x=f2bf(vv[0]); o.y=f2bf(vv[1]); o.z=f2bf(vv[2]); o.w=f2bf(vv[3]);
    *(ushort4*)(hb0+(long)r*KP+k)=o;
    *(ushort4*)(hb1+(long)r*KP+k)=o;
  }
}

// ---------- spatial + temporal attention (pre batch-softmax), per batch ----------
__global__ void k_attn(const float* __restrict__ X, const float* __restrict__ sa_W1,
   const float* __restrict__ sa_W2, const float* __restrict__ sa_W3,
   const float* __restrict__ sa_bs, const float* __restrict__ sa_Vs,
   const float* __restrict__ ta_U1, const float* __restrict__ ta_U2,
   const float* __restrict__ ta_U3, const float* __restrict__ ta_be,
   const float* __restrict__ ta_Ve,
   float* __restrict__ SA_pre, float* __restrict__ TA_pre){
  int b=blockIdx.x, tid=threadIdx.x;
  __shared__ float lin[864];            // raw X[b], layout [n][t][f]
  __shared__ float lhs[NN*TT];
  __shared__ float rhs[TT*NN];
  __shared__ float P[NN*NN];
  __shared__ float S[NN*NN];
  __shared__ float lhsT[TT*NN];
  __shared__ float rhsT[NN*TT];
  __shared__ float PT[TT*TT];
  __shared__ float E[TT*TT];
  for(int i=tid;i<864;i+=256) lin[i]=X[b*864+i];
  __syncthreads();
  for(int i=tid;i<NN*TT;i+=256){ int n=i/TT, t=i%TT;
    float acc=0;
    #pragma unroll
    for(int f=0;f<FF;f++){
      float t1=0;
      for(int u=0;u<TT;u++) t1 += lin[n*36+u*3+f]*sa_W1[u];
      acc += t1*sa_W2[f*TT+t];
    }
    lhs[n*TT+t]=acc;
    float r=0;
    #pragma unroll
    for(int f=0;f<FF;f++) r += sa_W3[f]*lin[n*36+t*3+f];
    rhs[t*NN+n]=r;
  }
  for(int i=tid;i<TT*NN;i+=256){ int t=i/NN, n=i%NN;
    float acc=0;
    #pragma unroll
    for(int f=0;f<FF;f++){
      float t1=0;
      for(int m=0;m<NN;m++) t1 += lin[m*36+t*3+f]*ta_U1[m];
      acc += t1*ta_U2[f*NN+n];
    }
    lhsT[t*NN+n]=acc;
    float r=0;
    #pragma unroll
    for(int f=0;f<FF;f++) r += ta_U3[f]*lin[n*36+t*3+f];
    rhsT[n*TT+t]=r;
  }
  __syncthreads();
  for(int i=tid;i<NN*NN;i+=256){ int n=i/NN,m=i%NN;
    float a=0;
    for(int t=0;t<TT;t++) a+=lhs[n*TT+t]*rhs[t*NN+m];
    P[i]=sigm(a+sa_bs[i]);
  }
  for(int i=tid;i<TT*TT;i+=256){ int t=i/TT,u=i%TT;
    float a=0;
    for(int n=0;n<NN;n++) a+=lhsT[t*NN+n]*rhsT[n*TT+u];
    PT[i]=sigm(a+ta_be[i]);
  }
  __syncthreads();
  for(int i=tid;i<NN*NN;i+=256){ int n=i/NN,k=i%NN;
    float a=0;
    for(int m=0;m<NN;m++) a+=sa_Vs[n*NN+m]*P[m*NN+k];
    S[i]=a;
  }
  for(int i=tid;i<TT*TT;i+=256){ int t=i/TT,v=i%TT;
    float a=0;
    for(int u=0;u<TT;u++) a+=ta_Ve[t*TT+u]*PT[u*TT+v];
    E[i]=a;
  }
  __syncthreads();
  if(tid<NN){ int k=tid;
    float mx=-1e30f;
    for(int n=0;n<NN;n++) mx=fmaxf(mx,S[n*NN+k]);
    float sm=0;
    for(int n=0;n<NN;n++) sm+=__expf(S[n*NN+k]-mx);
    for(int n=0;n<NN;n++){
      float v=__expf(S[n*NN+k]-mx)/sm;
      SA_pre[b*576+n*NN+k]=sigm(v);
    }
  }
  if(tid>=32 && tid<32+TT){ int v=tid-32;
    float mx=-1e30f;
    for(int t=0;t<TT;t++) mx=fmaxf(mx,E[t*TT+v]);
    float sm=0;
    for(int t=0;t<TT;t++) sm+=__expf(E[t*TT+v]-mx);
    for(int t=0;t<TT;t++){
      float e=__expf(E[t*TT+v]-mx)/sm;
      TA_pre[b*144+t*TT+v]=sigm(e);
    }
  }
}

// ---------- softmax over batch axis; s_a also written to OUTPUT as float ----------
__global__ void k_bsoftmax(const float* __restrict__ SA_pre, const float* __restrict__ TA_pre,
    float* __restrict__ s_a, float* __restrict__ t_a, float* __restrict__ out_sa){
  int i=blockIdx.x*blockDim.x+threadIdx.x;
  if(i<576){
    float mx=-1e30f;
    for(int b=0;b<BSZ;b++) mx=fmaxf(mx,SA_pre[b*576+i]);
    float sm=0;
    for(int b=0;b<BSZ;b++) sm+=__expf(SA_pre[b*576+i]-mx);
    for(int b=0;b<BSZ;b++){
      float v=__expf(SA_pre[b*576+i]-mx)/sm;
      s_a[b*576+i]=v;
      out_sa[b*576+i]=v;
    }
  } else if(i<720){
    int j=i-576;
    float mx=-1e30f;
    for(int b=0;b<BSZ;b++) mx=fmaxf(mx,TA_pre[b*144+j]);
    float sm=0;
    for(int b=0;b<BSZ;b++) sm+=__expf(TA_pre[b*144+j]-mx);
    for(int b=0;b<BSZ;b++) t_a[b*144+j]=__expf(TA_pre[b*144+j]-mx)/sm;
  }
}

// ---------- graph conv + LN + temporal mix + input layer, per batch ----------
__global__ void k_graph(const float* __restrict__ X, const float* __restrict__ cheb,
  const float* __restrict__ s_a, const float* __restrict__ t_a,
  const float* __restrict__ theta, const float* __restrict__ cheb_bias,
  const float* __restrict__ ln_g, const float* __restrict__ ln_b,
  const float* __restrict__ liw, const float* __restrict__ lib,
  float* __restrict__ x_in){
  int b=blockIdx.x, tid=threadIdx.x;
  __shared__ float lin[864];
  __shared__ float A2[KK*NN*NN];
  __shared__ float rg[KK*NN*FF*TT];
  __shared__ float xc[NN*COUT*TT];
  __shared__ float xres[DIN*TT];
  __shared__ float ta_s[TT*TT];
  for(int i=tid;i<864;i+=320) lin[i]=X[b*864+i];
  for(int i=tid;i<KK*NN*NN;i+=320){ int mn=i%576; A2[i]=cheb[i]*s_a[b*576+mn]; }
  for(int i=tid;i<144;i+=320) ta_s[i]=t_a[b*144+i];
  __syncthreads();
  for(int i=tid;i<KK*NN*FF*TT;i+=320){
    int t=i%TT, f=(i/TT)%FF, n=(i/36)%NN, k=i/864;
    float a=0;
    for(int m=0;m<NN;m++) a+=A2[k*576+m*NN+n]*lin[m*36+f*TT+t];
    rg[i]=a;
  }
  __syncthreads();
  for(int i=tid;i<NN*COUT*TT;i+=320){
    int t=i%TT, o=(i/TT)%COUT, n=i/(COUT*TT);
    float a=cheb_bias[o];
    #pragma unroll
    for(int k=0;k<KK;k++)
      #pragma unroll
      for(int f=0;f<FF;f++)
        a += rg[((k*NN+n)*FF+f)*TT+t]*theta[(k*FF+f)*COUT+o];
    xc[i]=fmaxf(a,0.f);
  }
  __syncthreads();
  if(tid<NN*COUT){
    float mu=0;
    for(int t=0;t<TT;t++) mu+=xc[tid*TT+t];
    mu*=(1.f/12.f);
    float var=0;
    for(int t=0;t<TT;t++){ float d=xc[tid*TT+t]-mu; var+=d*d; }
    var*=(1.f/12.f);
    float inv=rsqrtf(var+1e-5f);
    for(int t=0;t<TT;t++) xc[tid*TT+t]=(xc[tid*TT+t]-mu)*inv*ln_g[t]+ln_b[t];
  }
  __syncthreads();
  for(int i=tid;i<NN*COUT;i+=320){
    for(int v=0;v<TT;v++){
      float a=0;
      for(int t=0;t<TT;t++) a+=xc[i*TT+t]*ta_s[t*TT+v];
      xres[i*TT+v]=a;
    }
  }
  for(int i=tid;i<25*TT;i+=320){
    int r=i/TT, t=i%TT;
    float v=(r<NN)? lin[r*36+t*3+0] : lin[t*3+1];
    xres[(288+r)*TT+t]=v;
  }
  __syncthreads();
  for(int i=tid;i<DIN;i+=320){
    for(int t=0;t<TT;t++){
      float a=lib[t];
      #pragma unroll
      for(int u=0;u<TT;u++) a+=xres[i*TT+u]*liw[t*TT+u];
      x_in[((long)b*DIN+i)*TT+t]=a;
    }
  }
}

// ---------- per-(t,b): alpha softmax gate, xi -> bf16 padded [t*32+b][KPI] ----------
__global__ void __launch_bounds__(512) k_alpha(const float* __restrict__ x_in,
    const float* __restrict__ sa2_w, const float* __restrict__ sa2_b,
    unsigned short* __restrict__ xi_b){
  int blk=blockIdx.x; int t=blk>>5, b=blk&31; int tid=threadIdx.x;
  __shared__ float xt[DIN];
  __shared__ float red[512];
  if(tid<DIN) xt[tid]=x_in[((long)b*DIN+tid)*TT+t];
  __syncthreads();
  float z=-1e30f, e=0.f;
  if(tid<DIN){
    float a=sa2_b[tid];
    const float* wr=sa2_w+(long)tid*DIN;
    for(int i=0;i<DIN;i++) a+=xt[i]*wr[i];
    z=sigm(a);
  }
  red[tid]=z; __syncthreads();
  for(int off=256;off>0;off>>=1){ if(tid<off) red[tid]=fmaxf(red[tid],red[tid+off]); __syncthreads(); }
  float mx=red[0]; __syncthreads();
  e=(tid<DIN)?__expf(z-mx):0.f;
  red[tid]=e; __syncthreads();
  for(int off=256;off>0;off>>=1){ if(tid<off) red[tid]+=red[tid+off]; __syncthreads(); }
  float sm=red[0];
  if(tid<KPI){
    unsigned short v=0;
    if(tid<DIN){
      float alpha=e/sm;
      v=f2bf(xt[tid]*alpha+xt[tid]);
    }
    xi_b[(long)blk*KPI+tid]=v;
  }
}

// ---------- Gx[t][b][j] = xi @ W_ih^T + b_ih + b_hh (bf16 MFMA; W_ih fp32 read+cvt in regs) ----------
__global__ void __launch_bounds__(256) k_gx(const unsigned short* __restrict__ xi,
   const float* __restrict__ Wih, const float* __restrict__ b_ih,
   const float* __restrict__ b_hh, float* __restrict__ Gx){
  int w=threadIdx.x>>6, lane=threadIdx.x&63;
  int jt=blockIdx.x*4+w;
  if(jt>=NTILES) return;
  int j0=jt*32;
  int lj=lane&15, lk=lane>>4;
  short8 bfr[10][2];
  #pragma unroll
  for(int ks=0;ks<10;ks++)
    #pragma unroll
    for(int jh=0;jh<2;jh++){
      int j=j0+jh*16+lj;
      short8 bv;
      #pragma unroll
      for(int q=0;q<8;q++){
        int k=ks*32+lk*8+q;
        float f=(j<H4 && k<DIN)? Wih[(long)j*DIN+k] : 0.f;
        bv[q]=(short)f2bf(f);
      }
      bfr[ks][jh]=bv;
    }
  for(int t=0;t<TT;t++){
    f32x4 acc[2][2]={};
    #pragma unroll
    for(int ks=0;ks<10;ks++){
      #pragma unroll
      for(int mh=0;mh<2;mh++){
        short8 a=*(const short8*)(xi + ((long)(t*32+mh*16+lj))*KPI + ks*32 + lk*8);
        acc[mh][0]=mfma16(a,bfr[ks][0],acc[mh][0]);
        acc[mh][1]=mfma16(a,bfr[ks][1],acc[mh][1]);
      }
    }
    #pragma unroll
    for(int mh=0;mh<2;mh++)
      #pragma unroll
      for(int jh=0;jh<2;jh++){
        int j=j0+jh*16+lj;
        if(j<H4){
          float bias=b_ih[j]+b_hh[j];
          #pragma unroll
          for(int r=0;r<4;r++){
            int bb=mh*16+lk*4+r;     // C/D: col=lane&15, row=(lane>>4)*4+r  (m89-verified)
            Gx[((long)t*32+bb)*H4+j]=acc[mh][jh][r]+bias;
          }
        }
      }
  }
}

// ---------- fused LSTM step (bf16, PACKED W slabs: contiguous 1KB loads) ----------
__global__ void __launch_bounds__(512) k_step(const unsigned short* __restrict__ hb_r,
    unsigned short* __restrict__ hb_w, const unsigned short* __restrict__ Wp,
    const float* __restrict__ Gx, const float* __restrict__ c0,
    float* __restrict__ c, float* __restrict__ hs, int t){
  const int tid=threadIdx.x;
  const int w=tid>>6, lane=tid&63;
  const int j0=blockIdx.x*16;
  const int lj=lane&15, lk=lane>>4;
  const int s0=(118*w)>>3, s1=(118*(w+1))>>3;
  const unsigned short* slab = Wp + (long)blockIdx.x*64*KP;  // contiguous 483KB per block
  f32x4 acc[4][2]={};
  #pragma unroll 2
  for(int ks=s0;ks<s1;ks++){
    int kofs=ks*32+lk*8;
    short8 a0=*(const short8*)(hb_r + (long)lj*KP + kofs);
    short8 a1=*(const short8*)(hb_r + (long)(16+lj)*KP + kofs);
    const unsigned short* pk = slab + ((long)ks<<11);        // ks*4gates*512
    #pragma unroll
    for(int g=0;g<4;g++){
      short8 bv=*(const short8*)(pk + (g<<9) + (lane<<3));   // contiguous 1KB per wave-load
      acc[g][0]=mfma16(a0,bv,acc[g][0]);
      acc[g][1]=mfma16(a1,bv,acc[g][1]);
    }
  }
  __shared__ float red[8][4][512];
  #pragma unroll
  for(int g=0;g<4;g++)
    #pragma unroll
    for(int mh=0;mh<2;mh++)
      #pragma unroll
      for(int r=0;r<4;r++)
        red[w][g][(mh*16+lk*4+r)*16+lj]=acc[g][mh][r];
  __syncthreads();
  if(tid<512){
    int p=tid;
    int bb=p>>4, jl=p&15; int j=j0+jl;
    if(j<HID){
      long gxo=((long)t*BSZ+bb)*H4 + j;
      float si=0,sf=0,sg=0,so=0;
      #pragma unroll
      for(int ww=0;ww<8;ww++){
        si+=red[ww][0][p]; sf+=red[ww][1][p];
        sg+=red[ww][2][p]; so+=red[ww][3][p];
      }
      si+=Gx[gxo]; sf+=Gx[gxo+HID]; sg+=Gx[gxo+2*HID]; so+=Gx[gxo+3*HID];
      float gi=sigm(si), gf=sigm(sf), gg=tanhf(sg), go=sigm(so);
      int idx=bb*HID+j;
      float cin=(t==0)?c0[idx]:c[idx];
      float c2=gf*cin+gi*gg;
      float h2=go*tanhf(c2);
      c[idx]=c2;
      hs[(long)t*BSZ*HID+idx]=h2;
      hb_w[(long)bb*KP+j]=f2bf(h2);
    }
  }
}

// ---------- fused tail: beta softmax + weighted output ----------
__global__ void k_tail(const float* __restrict__ hs, const float* __restrict__ ta2_w,
   const float* __restrict__ ta2_b, const float* __restrict__ x_in,
   const float* __restrict__ out_w, const float* __restrict__ out_b,
   float* __restrict__ out0){
  int b=blockIdx.x, tid=threadIdx.x;
  float p[12]={0,0,0,0,0,0,0,0,0,0,0,0};
  for(int idx=tid; idx<TT*HID; idx+=256){
    int t=idx/HID, j=idx-t*HID;
    float v=hs[((long)t*BSZ+b)*HID+j];
    #pragma unroll
    for(int q=0;q<12;q++) p[q]+=v*ta2_w[(long)q*TT*HID+idx];
  }
  __shared__ float red[256];
  __shared__ float bt[12];
  float z[12];
  #pragma unroll
  for(int q=0;q<12;q++){
    __syncthreads();
    red[tid]=p[q]; __syncthreads();
    for(int off=128;off>0;off>>=1){ if(tid<off) red[tid]+=red[tid+off]; __syncthreads(); }
    z[q]=red[0];
  }
  if(tid==0){
    float mx=-1e30f;
    #pragma unroll
    for(int q=0;q<12;q++){ z[q]=fmaxf(z[q]+ta2_b[q],0.f); mx=fmaxf(mx,z[q]); }
    float sm=0;
    #pragma unroll
    for(int q=0;q<12;q++){ z[q]=__expf(z[q]-mx); sm+=z[q]; }
    #pragma unroll
    for(int q=0;q<12;q++) bt[q]=z[q]/sm;
  }
  __syncthreads();
  float acc=0;
  for(int j=tid;j<HID;j+=256){
    float ov=0;
    #pragma unroll
    for(int t=0;t<TT;t++) ov+=hs[((long)t*BSZ+b)*HID+j]*bt[t];
    ov+=x_in[(long)b*HID+j];
    acc+=fmaxf(ov,0.f)*out_w[j];
  }
  __syncthreads();
  red[tid]=acc; __syncthreads();
  for(int off=128;off>0;off>>=1){ if(tid<off) red[tid]+=red[tid+off]; __syncthreads(); }
  if(tid==0) out0[b]=red[0]+out_b[0];
}

extern "C" void kernel_launch(void* const* d_in, const int* in_sizes, int n_in,
                              void* d_out, int out_size, void* d_ws, size_t ws_size,
                              hipStream_t stream){
  (void)in_sizes; (void)n_in; (void)out_size; (void)ws_size;
  const float* X     =(const float*)d_in[0];
  const float* cheb  =(const float*)d_in[1];
  const float* sa_W1 =(const float*)d_in[2];
  const float* sa_W2 =(const float*)d_in[3];
  const float* sa_W3 =(const float*)d_in[4];
  const float* sa_bs =(const float*)d_in[5];
  const float* sa_Vs =(const float*)d_in[6];
  const float* ta_U1 =(const float*)d_in[7];
  const float* ta_U2 =(const float*)d_in[8];
  const float* ta_U3 =(const float*)d_in[9];
  const float* ta_be =(const float*)d_in[10];
  const float* ta_Ve =(const float*)d_in[11];
  const float* theta =(const float*)d_in[12];
  const float* cb    =(const float*)d_in[13];
  const float* ln_g  =(const float*)d_in[14];
  const float* ln_b  =(const float*)d_in[15];
  const float* liw   =(const float*)d_in[16];
  const float* lib   =(const float*)d_in[17];
  const float* sa2_w =(const float*)d_in[18];
  const float* sa2_b =(const float*)d_in[19];
  const float* W_ih  =(const float*)d_in[20];
  const float* W_hh  =(const float*)d_in[21];
  const float* b_ih  =(const float*)d_in[22];
  const float* b_hh  =(const float*)d_in[23];
  const float* ta2_w =(const float*)d_in[24];
  const float* ta2_b =(const float*)d_in[25];
  const float* out_w =(const float*)d_in[26];
  const float* out_b =(const float*)d_in[27];
  const float* h0    =(const float*)d_in[28];
  const float* c0    =(const float*)d_in[29];

  char* w=(char*)d_ws;
  unsigned short* Wp =(unsigned short*)(w);                   // NB*64*KP*2 = 113,582,080
  float* Gx   =(float*)(w+113582080);                         // 23,076,864 -> 136,658,944
  float* hs   =(float*)(w+136658944);                         //  5,769,216 -> 142,428,160
  unsigned short* hb0=(unsigned short*)(w+142428160);         //    241,664 -> 142,669,824
  unsigned short* hb1=(unsigned short*)(w+142669824);         //    241,664 -> 142,911,488
  float* c    =(float*)(w+142911488);                         //    480,768 -> 143,392,256
  float* x_in =(float*)(w+143392256);                         //    480,768 -> 143,873,024
  unsigned short* xi_b=(unsigned short*)(w+143873024);        //    245,760 -> 144,118,784
  float* SA   =(float*)(w+144118784);                         //     73,728
  float* TA   =(float*)(w+144192512);                         //     18,432
  float* s_a  =(float*)(w+144210944);                         //     73,728
  float* t_a  =(float*)(w+144284672);                         //     18,432
  float* out_f=(float*)d_out;                                 // [0..31]=out, [32..]=s_a

  k_convpack<<<dim3(NB,6),256,0,stream>>>(W_hh,Wp);
  k_convh<<<118,256,0,stream>>>(h0,hb0,hb1);
  k_attn<<<32,256,0,stream>>>(X,sa_W1,sa_W2,sa_W3,sa_bs,sa_Vs,ta_U1,ta_U2,ta_U3,ta_be,ta_Ve,SA,TA);
  k_bsoftmax<<<3,256,0,stream>>>(SA,TA,s_a,t_a,out_f+32);
  k_graph<<<32,320,0,stream>>>(X,cheb,s_a,t_a,theta,cb,ln_g,ln_b,liw,lib,x_in);
  k_alpha<<<384,512,0,stream>>>(x_in,sa2_w,sa2_b,xi_b);
  k_gx<<<118,256,0,stream>>>(xi_b,W_ih,b_ih,b_hh,Gx);
  unsigned short* hb[2]={hb0,hb1};
  for(int t=0;t<TT;t++)
    k_step<<<NB,512,0,stream>>>(hb[t&1],hb[(t+1)&1],Wp,Gx,c0,c,hs,t);
  k_tail<<<32,256,0,stream>>>(hs,ta2_w,ta2_b,x_in,out_w,out_b,out_f);
}